// Round 6
// baseline (379.760 us; speedup 1.0000x reference)
//
#include <hip/hip_runtime.h>
#include <math.h>

#define NB 8
#define NP 4096
#define TOPK 10
#define KNB 9
#define QPB 16              // queries per block
#define SLC 8               // candidate slices per query
#define NT 4                // candidate tiles
#define TPTS 1024           // points per tile
#define QPT (TPTS / SLC)    // 128 candidates per (tile, slice)
#define TSTR 129            // slice stride in float4 (128 + 1 -> slice base bank 4s, disjoint quads)
#define MST 81              // svD/svI row stride (odd -> conflict-free strided reads)

#define FINF 3.0e38f
#define IINF 0x7fffffff
#define PI_F 3.14159274101257324f

__global__ __launch_bounds__(128, 2)
void repsurf_knn(const float* __restrict__ x,
                 const float* __restrict__ cw1,
                 const float* __restrict__ bg1, const float* __restrict__ bb1,
                 const float* __restrict__ bm1, const float* __restrict__ bv1,
                 const float* __restrict__ cw2, const float* __restrict__ cb2,
                 const float* __restrict__ bg2, const float* __restrict__ bb2,
                 const float* __restrict__ bm2, const float* __restrict__ bv2,
                 const float* __restrict__ cw3, const float* __restrict__ cb3,
                 float* __restrict__ out)
{
    __shared__ __align__(16) float4 tile[SLC * TSTR];      // 16512 B
    __shared__ float svD[QPB * MST];                       // sorted dist runs, rows of 81
    __shared__ int   svI[QPB * MST];                       // matching indices (prefix-filled)
    __shared__ float Tst[QPB];                             // exact union 10th per query
    __shared__ __align__(16) float sW1[9 * 12];
    __shared__ __align__(16) float sW2[9 * 12];
    __shared__ __align__(16) float sW3[9 * 12];
    __shared__ float sSh1[9], sSh2[9], sSh3[9];

    const int t  = threadIdx.x;
    const int b  = blockIdx.x >> 8;          // 256 chunks per batch
    const int qc = blockIdx.x & 255;
    const float* xb = x + (size_t)b * 3 * NP;

    // ---- fold BN into conv weights ----
    if (t < 108) {
        int o = t / 12, c = t % 12;
        float w1v = 0.f, w2v = 0.f, w3v = 0.f;
        if (c < 9) {
            float iv1 = bg1[o] * rsqrtf(bv1[o] + 1e-5f);
            float iv2 = bg2[o] * rsqrtf(bv2[o] + 1e-5f);
            w1v = cw1[o * 9 + c] * iv1;
            w2v = cw2[o * 9 + c] * iv2;
            w3v = cw3[o * 9 + c];
        }
        sW1[t] = w1v; sW2[t] = w2v; sW3[t] = w3v;
        if (t < 9) {
            float iv1 = bg1[t] * rsqrtf(bv1[t] + 1e-5f);
            float iv2 = bg2[t] * rsqrtf(bv2[t] + 1e-5f);
            sSh1[t] = bb1[t] - bm1[t] * iv1;
            sSh2[t] = cb2[t] * iv2 + bb2[t] - bm2[t] * iv2;
            sSh3[t] = cb3[t];
        }
    }

    const int q  = t & (QPB - 1);
    const int s  = t >> 4;                   // slice 0..7
    const int qi = qc * QPB + q;
    const float qx = xb[qi], qy = xb[NP + qi], qz = xb[2 * NP + qi];

// identical expression in both phases (bit-exact match required)
#define DIST(P) fmaf((P).x - qx, (P).x - qx, fmaf((P).y - qy, (P).y - qy, ((P).z - qz) * ((P).z - qz)))

// branchless distance-only sorted insert (19 fmin/fmax, full ILP)
#define CH1(P) do { \
        float _d = DIST(P); \
        _Pragma("unroll") \
        for (int jj = TOPK - 1; jj > 0; --jj) \
            dk[jj] = fminf(dk[jj], fmaxf(dk[jj - 1], _d)); \
        dk[0] = fminf(dk[0], _d); } while (0)

// vectorized AoS tile staging: 6 float4 global loads + 8 float4 LDS writes per thread
#define STAGE(TT) do { \
        _Pragma("unroll") \
        for (int r = 0; r < 2; ++r) { \
            int f4 = r * 128 + t; \
            float4 X = ((const float4*)(xb))[(TT) * 256 + f4]; \
            float4 Y = ((const float4*)(xb + NP))[(TT) * 256 + f4]; \
            float4 Z = ((const float4*)(xb + 2 * NP))[(TT) * 256 + f4]; \
            int p0 = f4 * 4; \
            tile[((p0 + 0) >> 7) * TSTR + ((p0 + 0) & 127)] = make_float4(X.x, Y.x, Z.x, 0.f); \
            tile[((p0 + 1) >> 7) * TSTR + ((p0 + 1) & 127)] = make_float4(X.y, Y.y, Z.y, 0.f); \
            tile[((p0 + 2) >> 7) * TSTR + ((p0 + 2) & 127)] = make_float4(X.z, Y.z, Z.z, 0.f); \
            tile[((p0 + 3) >> 7) * TSTR + ((p0 + 3) & 127)] = make_float4(X.w, Y.w, Z.w, 0.f); \
        } } while (0)

    float dk[TOPK];
#pragma unroll
    for (int j = 0; j < TOPK; ++j) dk[j] = FINF;

    // ---- phase 1: branchless top-10 distances per (query, slice) ----
    for (int tt = 0; tt < NT; ++tt) {
        __syncthreads();
        STAGE(tt);
        __syncthreads();
        const float4* ts = tile + s * TSTR;
        for (int g = 0; g < QPT / 4; ++g) {
            float4 P0 = ts[g * 4 + 0];
            float4 P1 = ts[g * 4 + 1];
            float4 P2 = ts[g * 4 + 2];
            float4 P3 = ts[g * 4 + 3];
            CH1(P0); CH1(P1); CH1(P2); CH1(P3);
        }
    }

    // ---- write sorted distance runs; compute exact union 10th T* ----
    const int rb = q * MST + s * TOPK;
#pragma unroll
    for (int j = 0; j < TOPK; ++j) svD[rb + j] = dk[j];
    __syncthreads();

    if (t < QPB) {
        // value-only 8-way merge, 10 picks; heads stay in bounds (<=10 picks total)
        int p0 = 0, p1 = 0, p2 = 0, p3 = 0, p4 = 0, p5 = 0, p6 = 0, p7 = 0;
        const int mbq = t * MST;
        float last = 0.f;
#pragma unroll
        for (int j = 0; j < TOPK; ++j) {
            float v0 = svD[mbq + 0 * TOPK + p0];
            float v1 = svD[mbq + 1 * TOPK + p1];
            float v2 = svD[mbq + 2 * TOPK + p2];
            float v3 = svD[mbq + 3 * TOPK + p3];
            float v4 = svD[mbq + 4 * TOPK + p4];
            float v5 = svD[mbq + 5 * TOPK + p5];
            float v6 = svD[mbq + 6 * TOPK + p6];
            float v7 = svD[mbq + 7 * TOPK + p7];
            float m01 = fminf(v0, v1), m23 = fminf(v2, v3);
            float m45 = fminf(v4, v5), m67 = fminf(v6, v7);
            float m03 = fminf(m01, m23), m47 = fminf(m45, m67);
            float mv  = fminf(m03, m47);
            last = mv;
            bool a0 = (v0 == mv);
            bool a1 = (v1 == mv) && !a0;
            bool a2 = (v2 == mv) && !(a0 | a1);
            bool a3 = (v3 == mv) && !(a0 | a1 | a2);
            bool a4 = (v4 == mv) && !(a0 | a1 | a2 | a3);
            bool a5 = (v5 == mv) && !(a0 | a1 | a2 | a3 | a4);
            bool a6 = (v6 == mv) && !(a0 | a1 | a2 | a3 | a4 | a5);
            bool a7 = (v7 == mv) && !(a0 | a1 | a2 | a3 | a4 | a5 | a6);
            p0 += a0; p1 += a1; p2 += a2; p3 += a3;
            p4 += a4; p5 += a5; p6 += a6; p7 += a7;
        }
        Tst[t] = last;
    }
#pragma unroll
    for (int i = t; i < QPB * MST; i += 128) svI[i] = IINF;
    __syncthreads();

    const float Tq = Tst[q];

// phase-2 body: survivor's rank within this lane's sorted dk = its slot; write index only.
// svI row is PRIVATE to this lane; the poll handles exact-distance ties safely.
#define CH2(P, IDX) do { \
        float _d = DIST(P); \
        if (_d <= Tq) { \
            int rk = 0; \
            _Pragma("unroll") \
            for (int jj = 0; jj < TOPK - 1; ++jj) rk += (dk[jj] < _d); \
            while (rk < TOPK - 1 && svI[rb + rk] != IINF) ++rk; \
            if (svI[rb + rk] == IINF) svI[rb + rk] = (IDX); \
        } } while (0)

    // ---- phase 2: filtered rescan writing indices ----
    for (int tt = 0; tt < NT; ++tt) {
        __syncthreads();
        STAGE(tt);
        __syncthreads();
        const float4* ts = tile + s * TSTR;
        const int cb = tt * TPTS + s * QPT;
        for (int g = 0; g < QPT / 4; ++g) {
            float4 P0 = ts[g * 4 + 0];
            float4 P1 = ts[g * 4 + 1];
            float4 P2 = ts[g * 4 + 2];
            float4 P3 = ts[g * 4 + 3];
            CH2(P0, cb + g * 4 + 0);
            CH2(P1, cb + g * 4 + 1);
            CH2(P2, cb + g * 4 + 2);
            CH2(P3, cb + g * 4 + 3);
        }
    }
    __syncthreads();

    // ---- phase 3: 8-way (d, idx) merge + geometry + MLP (16 lanes) ----
    if (t < QPB) {
        const int qb = t * MST;
        int ni[KNB];
        int p0 = 0, p1 = 0, p2 = 0, p3 = 0, p4 = 0, p5 = 0, p6 = 0, p7 = 0;
#pragma unroll
        for (int j = 0; j < TOPK; ++j) {
#define GETH(K) float d##K; int i##K; \
            { int pk = p##K; \
              if (pk < TOPK) { d##K = svD[qb + K * TOPK + pk]; i##K = svI[qb + K * TOPK + pk]; } \
              else { d##K = FINF; i##K = IINF; } }
            GETH(0) GETH(1) GETH(2) GETH(3) GETH(4) GETH(5) GETH(6) GETH(7)
#undef GETH
#define WIN(DA, IA, SA, DB, IB, SB, DO_, IO_, SO_) \
            bool w_##SO_ = ((DA) < (DB)) || ((DA) == (DB) && (IA) < (IB)); \
            float DO_ = w_##SO_ ? (DA) : (DB); \
            int IO_ = w_##SO_ ? (IA) : (IB); \
            int SO_ = w_##SO_ ? (SA) : (SB);
            WIN(d0, i0, 0, d1, i1, 1, dA, iA, sA)
            WIN(d2, i2, 2, d3, i3, 3, dB, iB, sB)
            WIN(d4, i4, 4, d5, i5, 5, dC, iC, sC)
            WIN(d6, i6, 6, d7, i7, 7, dD, iD, sD)
            WIN(dA, iA, sA, dB, iB, sB, dE, iE, sE)
            WIN(dC, iC, sC, dD, iD, sD, dF, iF, sF)
            WIN(dE, iE, sE, dF, iF, sF, dG, iG, sw)
            (void)dG; (void)iG;
#undef WIN
            if (j > 0) ni[j - 1] = iG;      // drop entry 0 == self (d = 0)
            p0 += (sw == 0); p1 += (sw == 1); p2 += (sw == 2); p3 += (sw == 3);
            p4 += (sw == 4); p5 += (sw == 5); p6 += (sw == 6); p7 += (sw == 7);
        }

        float gx[KNB], gy[KNB], gz[KNB], kk[KNB];
#pragma unroll
        for (int j = 0; j < KNB; ++j) {
            int id = ni[j];
            gx[j] = xb[id] - qx;
            gy[j] = xb[NP + id] - qy;
            gz[j] = xb[2 * NP + id] - qz;
            kk[j] = atan2f(gy[j], gx[j]);
        }
#pragma unroll
        for (int pass = 0; pass < KNB - 1; ++pass) {
#pragma unroll
            for (int j = 0; j < KNB - 1 - pass; ++j) {
                if (kk[j + 1] < kk[j]) {
                    float tv;
                    tv = kk[j]; kk[j] = kk[j + 1]; kk[j + 1] = tv;
                    tv = gx[j]; gx[j] = gx[j + 1]; gx[j + 1] = tv;
                    tv = gy[j]; gy[j] = gy[j + 1]; gy[j + 1] = tv;
                    tv = gz[j]; gz[j] = gz[j + 1]; gz[j + 1] = tv;
                }
            }
        }

        float ux[KNB], uy[KNB], uz[KNB];
#pragma unroll
        for (int j = 0; j < KNB; ++j) {
            int j2 = (j + 1 == KNB) ? 0 : j + 1;
            float nx_ = gy[j] * gz[j2] - gz[j] * gy[j2];
            float ny_ = gz[j] * gx[j2] - gx[j] * gz[j2];
            float nz_ = gx[j] * gy[j2] - gy[j] * gx[j2];
            float ln = sqrtf(nx_ * nx_ + ny_ * ny_ + nz_ * nz_);
            float inv = 1.0f / fmaxf(ln, 1e-10f);
            ux[j] = nx_ * inv; uy[j] = ny_ * inv; uz[j] = nz_ * inv;
        }
        float sgn = (ux[0] > 0.0f) ? 1.0f : -1.0f;

        const float4* W1v = (const float4*)sW1;
        const float4* W2v = (const float4*)sW2;
        const float4* W3v = (const float4*)sW3;

#define DOT9(WV, O, V) ( \
        (WV)[(O)*3+0].x * (V)[0] + (WV)[(O)*3+0].y * (V)[1] + \
        (WV)[(O)*3+0].z * (V)[2] + (WV)[(O)*3+0].w * (V)[3] + \
        (WV)[(O)*3+1].x * (V)[4] + (WV)[(O)*3+1].y * (V)[5] + \
        (WV)[(O)*3+1].z * (V)[6] + (WV)[(O)*3+1].w * (V)[7] + \
        (WV)[(O)*3+2].x * (V)[8] )

        float acc[9];
#pragma unroll
        for (int o = 0; o < 9; ++o) acc[o] = 0.0f;

#pragma unroll
        for (int j = 0; j < KNB; ++j) {
            int j2 = (j + 1 == KNB) ? 0 : j + 1;
            float cx = (gx[j] + gx[j2]) * (1.0f / 3.0f);
            float cy = (gy[j] + gy[j2]) * (1.0f / 3.0f);
            float cz = (gz[j] + gz[j2]) * (1.0f / 3.0f);
            float rho = sqrtf(cx * cx + cy * cy + cz * cz);
            float rs  = fmaxf(rho, 1e-8f);
            float ct  = fminf(fmaxf(cz / rs, -1.0f), 1.0f);
            float th  = acosf(ct) / PI_F;
            float ph  = atan2f(cy, cx) / (2.0f * PI_F) + 0.5f;
            float f[9]  = {cx, cy, cz, rho, th, ph, ux[j] * sgn, uy[j] * sgn, uz[j] * sgn};
            float t1[9], t2[9];
#pragma unroll
            for (int o = 0; o < 9; ++o)
                t1[o] = fmaxf(DOT9(W1v, o, f) + sSh1[o], 0.0f);
#pragma unroll
            for (int o = 0; o < 9; ++o)
                t2[o] = fmaxf(DOT9(W2v, o, t1) + sSh2[o], 0.0f);
#pragma unroll
            for (int o = 0; o < 9; ++o)
                acc[o] += DOT9(W3v, o, t2);
        }

        float* ob = out + (size_t)b * 9 * NP;
#pragma unroll
        for (int o = 0; o < 9; ++o)
            ob[o * NP + qi] = acc[o] + 9.0f * sSh3[o];
    }
}

extern "C" void kernel_launch(void* const* d_in, const int* in_sizes, int n_in,
                              void* d_out, int out_size, void* d_ws, size_t ws_size,
                              hipStream_t stream) {
    const float* x   = (const float*)d_in[0];
    const float* cw1 = (const float*)d_in[1];
    const float* bg1 = (const float*)d_in[2];
    const float* bb1 = (const float*)d_in[3];
    const float* bm1 = (const float*)d_in[4];
    const float* bv1 = (const float*)d_in[5];
    const float* cw2 = (const float*)d_in[6];
    const float* cb2 = (const float*)d_in[7];
    const float* bg2 = (const float*)d_in[8];
    const float* bb2 = (const float*)d_in[9];
    const float* bm2 = (const float*)d_in[10];
    const float* bv2 = (const float*)d_in[11];
    const float* cw3 = (const float*)d_in[12];
    const float* cb3 = (const float*)d_in[13];
    float* out = (float*)d_out;

    hipLaunchKernelGGL(repsurf_knn, dim3(NB * (NP / QPB)), dim3(128), 0, stream,
                       x, cw1, bg1, bb1, bm1, bv1, cw2, cb2, bg2, bb2, bm2, bv2,
                       cw3, cb3, out);
}

// Round 7
// 290.008 us; speedup vs baseline: 1.3095x; 1.3095x over previous
//
#include <hip/hip_runtime.h>
#include <math.h>

#define NB 8
#define NP 4096
#define NQ (NB * NP)        // 32768 queries total
#define TOPK 10
#define KNB 9
#define QPB 16              // queries per block (K1)
#define SLC 8               // candidate slices per query
#define NT 4                // candidate tiles
#define TPTS 1024           // points per tile
#define QPT (TPTS / SLC)    // 128 candidates per (tile, slice)
#define MST 81              // svD/svI row stride (17t%32 distinct for 16 rows)

#define FINF 3.0e38f
#define IINF 0x7fffffff
#define PI_F 3.14159274101257324f

// ======================= K1: exact 10-NN indices =======================
__global__ __launch_bounds__(128, 4)
void knn_idx(const float* __restrict__ x, int* __restrict__ nbr)
{
    __shared__ __align__(16) float tileF[3 * 1056];   // v2-verified quarter-staggered tile (12672 B)
    __shared__ float svD[QPB * MST];                  // per-(q,s) sorted distance runs
    __shared__ int   svI[QPB * MST];                  // survivor indices (prefix-filled)
    __shared__ float Tst[QPB];                        // exact union 10th per query

    const int t  = threadIdx.x;
    const int b  = blockIdx.x >> 8;          // 256 chunks per batch
    const int qc = blockIdx.x & 255;
    const float* xb = x + (size_t)b * 3 * NP;

    const int q  = t & (QPB - 1);
    const int s  = t >> 4;                   // slice 0..7
    const int qi = qc * QPB + q;
    const float qx = xb[qi], qy = xb[NP + qi], qz = xb[2 * NP + qi];

// v2-verified staging: 6 coalesced float4 loads -> quarter-staggered SoA layout
#define STAGE(TT) do { \
        const float* src0 = xb + (TT) * TPTS; \
        _Pragma("unroll") \
        for (int r = 0; r < 6; ++r) { \
            int f = r * 128 + t; \
            int c = f >> 8, o = f & 255; \
            float4 v = *(const float4*)(src0 + c * NP + o * 4); \
            ((float4*)tileF)[c * 264 + (o >> 5) * 33 + (o & 31)] = v; \
        } } while (0)

// identical distance expression in both phases (bit-exact match required)
#define DSTX(X, Y, Z) fmaf((X) - qx, (X) - qx, fmaf((Y) - qy, (Y) - qy, ((Z) - qz) * ((Z) - qz)))

// med3 sorted-distance insert: dk[jj] = median(d, dk[jj-1], dk[jj]) == min(dk[jj], max(dk[jj-1], d))
#define CH1(X, Y, Z) do { \
        float _d = DSTX(X, Y, Z); \
        _Pragma("unroll") \
        for (int jj = TOPK - 1; jj > 0; --jj) \
            dk[jj] = __builtin_amdgcn_fmed3f(_d, dk[jj - 1], dk[jj]); \
        dk[0] = fminf(dk[0], _d); } while (0)

    float dk[TOPK];
#pragma unroll
    for (int j = 0; j < TOPK; ++j) dk[j] = FINF;

    // ---- phase 1: branchless top-10 distances per (query, slice) ----
    for (int tt = 0; tt < NT; ++tt) {
        __syncthreads();
        STAGE(tt);
        __syncthreads();
        const float4* tx4 = (const float4*)tileF + s * 33;
        const float4* ty4 = (const float4*)tileF + 264 + s * 33;
        const float4* tz4 = (const float4*)tileF + 528 + s * 33;
        for (int mm = 0; mm < QPT / 4; ++mm) {
            float4 X = tx4[mm];
            float4 Y = ty4[mm];
            float4 Z = tz4[mm];
            CH1(X.x, Y.x, Z.x);
            CH1(X.y, Y.y, Z.y);
            CH1(X.z, Y.z, Z.z);
            CH1(X.w, Y.w, Z.w);
        }
    }

    // ---- exact union 10th T* per query ----
    const int rb = q * MST + s * TOPK;
#pragma unroll
    for (int j = 0; j < TOPK; ++j) svD[rb + j] = dk[j];
    __syncthreads();

    if (t < QPB) {
        int p0 = 0, p1 = 0, p2 = 0, p3 = 0, p4 = 0, p5 = 0, p6 = 0, p7 = 0;
        const int mbq = t * MST;
        float last = 0.f;
#pragma unroll
        for (int j = 0; j < TOPK; ++j) {
            float v0 = svD[mbq + 0 * TOPK + p0];
            float v1 = svD[mbq + 1 * TOPK + p1];
            float v2 = svD[mbq + 2 * TOPK + p2];
            float v3 = svD[mbq + 3 * TOPK + p3];
            float v4 = svD[mbq + 4 * TOPK + p4];
            float v5 = svD[mbq + 5 * TOPK + p5];
            float v6 = svD[mbq + 6 * TOPK + p6];
            float v7 = svD[mbq + 7 * TOPK + p7];
            float m01 = fminf(v0, v1), m23 = fminf(v2, v3);
            float m45 = fminf(v4, v5), m67 = fminf(v6, v7);
            float mv  = fminf(fminf(m01, m23), fminf(m45, m67));
            last = mv;
            bool a0 = (v0 == mv);
            bool a1 = (v1 == mv) && !a0;
            bool a2 = (v2 == mv) && !(a0 | a1);
            bool a3 = (v3 == mv) && !(a0 | a1 | a2);
            bool a4 = (v4 == mv) && !(a0 | a1 | a2 | a3);
            bool a5 = (v5 == mv) && !(a0 | a1 | a2 | a3 | a4);
            bool a6 = (v6 == mv) && !(a0 | a1 | a2 | a3 | a4 | a5);
            bool a7 = (v7 == mv) && !(a0 | a1 | a2 | a3 | a4 | a5 | a6);
            p0 += a0; p1 += a1; p2 += a2; p3 += a3;
            p4 += a4; p5 += a5; p6 += a6; p7 += a7;
        }
        Tst[t] = last;
    }
    for (int i = t; i < QPB * MST; i += 128) svI[i] = IINF;
    __syncthreads();

    const float Tq = Tst[q];

// survivor (rare, ~1.3/lane): rank in this lane's sorted dk = slot; poll past equal-tie slots
#define CH2(X, Y, Z, IDX) do { \
        float _d = DSTX(X, Y, Z); \
        if (_d <= Tq) { \
            int rk = 0; \
            _Pragma("unroll") \
            for (int jj = 0; jj < TOPK - 1; ++jj) rk += (dk[jj] < _d); \
            while (rk < TOPK - 1 && svI[rb + rk] != IINF) ++rk; \
            if (svI[rb + rk] == IINF) svI[rb + rk] = (IDX); \
        } } while (0)

    // ---- phase 2: filtered rescan writing indices (ascending order -> top_k tie-break) ----
    for (int tt = 0; tt < NT; ++tt) {
        __syncthreads();
        STAGE(tt);
        __syncthreads();
        const float4* tx4 = (const float4*)tileF + s * 33;
        const float4* ty4 = (const float4*)tileF + 264 + s * 33;
        const float4* tz4 = (const float4*)tileF + 528 + s * 33;
        const int cb = tt * TPTS + s * QPT;
        for (int mm = 0; mm < QPT / 4; ++mm) {
            float4 X = tx4[mm];
            float4 Y = ty4[mm];
            float4 Z = tz4[mm];
            CH2(X.x, Y.x, Z.x, cb + mm * 4 + 0);
            CH2(X.y, Y.y, Z.y, cb + mm * 4 + 1);
            CH2(X.z, Y.z, Z.z, cb + mm * 4 + 2);
            CH2(X.w, Y.w, Z.w, cb + mm * 4 + 3);
        }
    }
    __syncthreads();

    // ---- 8-way (d, idx) merge; write neighbor indices 1..9 (drop self) ----
    if (t < QPB) {
        const int qb = t * MST;
        int p0 = 0, p1 = 0, p2 = 0, p3 = 0, p4 = 0, p5 = 0, p6 = 0, p7 = 0;
        const int gq = b * NP + qi;
#pragma unroll
        for (int j = 0; j < TOPK; ++j) {
#define GETH(K) float d##K; int i##K; \
            { int pk = p##K; \
              if (pk < TOPK) { d##K = svD[qb + K * TOPK + pk]; i##K = svI[qb + K * TOPK + pk]; } \
              else { d##K = FINF; i##K = IINF; } }
            GETH(0) GETH(1) GETH(2) GETH(3) GETH(4) GETH(5) GETH(6) GETH(7)
#undef GETH
#define WIN(DA, IA, SA, DB, IB, SB, DO_, IO_, SO_) \
            bool w_##SO_ = ((DA) < (DB)) || ((DA) == (DB) && (IA) < (IB)); \
            float DO_ = w_##SO_ ? (DA) : (DB); \
            int IO_ = w_##SO_ ? (IA) : (IB); \
            int SO_ = w_##SO_ ? (SA) : (SB);
            WIN(d0, i0, 0, d1, i1, 1, dA, iA, sA)
            WIN(d2, i2, 2, d3, i3, 3, dB, iB, sB)
            WIN(d4, i4, 4, d5, i5, 5, dC, iC, sC)
            WIN(d6, i6, 6, d7, i7, 7, dD, iD, sD)
            WIN(dA, iA, sA, dB, iB, sB, dE, iE, sE)
            WIN(dC, iC, sC, dD, iD, sD, dF, iF, sF)
            WIN(dE, iE, sE, dF, iF, sF, dG, iG, sw)
            (void)dG;
#undef WIN
            if (j > 0) nbr[(j - 1) * NQ + gq] = iG;
            p0 += (sw == 0); p1 += (sw == 1); p2 += (sw == 2); p3 += (sw == 3);
            p4 += (sw == 4); p5 += (sw == 5); p6 += (sw == 6); p7 += (sw == 7);
        }
    }
}

// ======================= K2: geometry + MLP =======================
__global__ __launch_bounds__(64, 2)
void umb_feat(const float* __restrict__ x, const int* __restrict__ nbr,
              const float* __restrict__ cw1,
              const float* __restrict__ bg1, const float* __restrict__ bb1,
              const float* __restrict__ bm1, const float* __restrict__ bv1,
              const float* __restrict__ cw2, const float* __restrict__ cb2,
              const float* __restrict__ bg2, const float* __restrict__ bb2,
              const float* __restrict__ bm2, const float* __restrict__ bv2,
              const float* __restrict__ cw3, const float* __restrict__ cb3,
              float* __restrict__ out)
{
    __shared__ __align__(16) float sW1[9 * 12];
    __shared__ __align__(16) float sW2[9 * 12];
    __shared__ __align__(16) float sW3[9 * 12];
    __shared__ float sSh1[9], sSh2[9], sSh3[9];

    const int t = threadIdx.x;
    for (int i = t; i < 108; i += 64) {
        int o = i / 12, c = i % 12;
        float w1v = 0.f, w2v = 0.f, w3v = 0.f;
        if (c < 9) {
            float iv1 = bg1[o] * rsqrtf(bv1[o] + 1e-5f);
            float iv2 = bg2[o] * rsqrtf(bv2[o] + 1e-5f);
            w1v = cw1[o * 9 + c] * iv1;
            w2v = cw2[o * 9 + c] * iv2;
            w3v = cw3[o * 9 + c];
        }
        sW1[i] = w1v; sW2[i] = w2v; sW3[i] = w3v;
        if (i < 9) {
            float iv1 = bg1[i] * rsqrtf(bv1[i] + 1e-5f);
            float iv2 = bg2[i] * rsqrtf(bv2[i] + 1e-5f);
            sSh1[i] = bb1[i] - bm1[i] * iv1;
            sSh2[i] = cb2[i] * iv2 + bb2[i] - bm2[i] * iv2;
            sSh3[i] = cb3[i];
        }
    }
    __syncthreads();

    const int gq = blockIdx.x * 64 + t;      // 0..NQ-1
    const int b  = gq >> 12;
    const int qi = gq & (NP - 1);
    const float* xb = x + (size_t)b * 3 * NP;
    const float qx = xb[qi], qy = xb[NP + qi], qz = xb[2 * NP + qi];

    float gx[KNB], gy[KNB], gz[KNB], kk[KNB];
#pragma unroll
    for (int j = 0; j < KNB; ++j) {
        int id = nbr[j * NQ + gq];
        gx[j] = xb[id] - qx;
        gy[j] = xb[NP + id] - qy;
        gz[j] = xb[2 * NP + id] - qz;
        kk[j] = atan2f(gy[j], gx[j]);        // monotone in reference phi
    }
    // stable bubble sort by azimuth
#pragma unroll
    for (int pass = 0; pass < KNB - 1; ++pass) {
#pragma unroll
        for (int j = 0; j < KNB - 1 - pass; ++j) {
            if (kk[j + 1] < kk[j]) {
                float tv;
                tv = kk[j]; kk[j] = kk[j + 1]; kk[j + 1] = tv;
                tv = gx[j]; gx[j] = gx[j + 1]; gx[j + 1] = tv;
                tv = gy[j]; gy[j] = gy[j + 1]; gy[j + 1] = tv;
                tv = gz[j]; gz[j] = gz[j + 1]; gz[j + 1] = tv;
            }
        }
    }

    float ux[KNB], uy[KNB], uz[KNB];
#pragma unroll
    for (int j = 0; j < KNB; ++j) {
        int j2 = (j + 1 == KNB) ? 0 : j + 1;
        float nx_ = gy[j] * gz[j2] - gz[j] * gy[j2];
        float ny_ = gz[j] * gx[j2] - gx[j] * gz[j2];
        float nz_ = gx[j] * gy[j2] - gy[j] * gx[j2];
        float ln = sqrtf(nx_ * nx_ + ny_ * ny_ + nz_ * nz_);
        float inv = 1.0f / fmaxf(ln, 1e-10f);
        ux[j] = nx_ * inv; uy[j] = ny_ * inv; uz[j] = nz_ * inv;
    }
    float sgn = (ux[0] > 0.0f) ? 1.0f : -1.0f;

    const float4* W1v = (const float4*)sW1;
    const float4* W2v = (const float4*)sW2;
    const float4* W3v = (const float4*)sW3;

#define DOT9(WV, O, V) ( \
    (WV)[(O)*3+0].x * (V)[0] + (WV)[(O)*3+0].y * (V)[1] + \
    (WV)[(O)*3+0].z * (V)[2] + (WV)[(O)*3+0].w * (V)[3] + \
    (WV)[(O)*3+1].x * (V)[4] + (WV)[(O)*3+1].y * (V)[5] + \
    (WV)[(O)*3+1].z * (V)[6] + (WV)[(O)*3+1].w * (V)[7] + \
    (WV)[(O)*3+2].x * (V)[8] )

    float acc[9];
#pragma unroll
    for (int o = 0; o < 9; ++o) acc[o] = 0.0f;

#pragma unroll
    for (int j = 0; j < KNB; ++j) {
        int j2 = (j + 1 == KNB) ? 0 : j + 1;
        float cx = (gx[j] + gx[j2]) * (1.0f / 3.0f);
        float cy = (gy[j] + gy[j2]) * (1.0f / 3.0f);
        float cz = (gz[j] + gz[j2]) * (1.0f / 3.0f);
        float rho = sqrtf(cx * cx + cy * cy + cz * cz);
        float rs  = fmaxf(rho, 1e-8f);
        float ct  = fminf(fmaxf(cz / rs, -1.0f), 1.0f);
        float th  = acosf(ct) / PI_F;
        float ph  = atan2f(cy, cx) / (2.0f * PI_F) + 0.5f;
        float f[9]  = {cx, cy, cz, rho, th, ph, ux[j] * sgn, uy[j] * sgn, uz[j] * sgn};
        float t1[9], t2[9];
#pragma unroll
        for (int o = 0; o < 9; ++o)
            t1[o] = fmaxf(DOT9(W1v, o, f) + sSh1[o], 0.0f);
#pragma unroll
        for (int o = 0; o < 9; ++o)
            t2[o] = fmaxf(DOT9(W2v, o, t1) + sSh2[o], 0.0f);
#pragma unroll
        for (int o = 0; o < 9; ++o)
            acc[o] += DOT9(W3v, o, t2);
    }

    float* ob = out + (size_t)b * 9 * NP;
#pragma unroll
    for (int o = 0; o < 9; ++o)
        ob[o * NP + qi] = acc[o] + 9.0f * sSh3[o];
}

extern "C" void kernel_launch(void* const* d_in, const int* in_sizes, int n_in,
                              void* d_out, int out_size, void* d_ws, size_t ws_size,
                              hipStream_t stream) {
    const float* x   = (const float*)d_in[0];
    const float* cw1 = (const float*)d_in[1];
    const float* bg1 = (const float*)d_in[2];
    const float* bb1 = (const float*)d_in[3];
    const float* bm1 = (const float*)d_in[4];
    const float* bv1 = (const float*)d_in[5];
    const float* cw2 = (const float*)d_in[6];
    const float* cb2 = (const float*)d_in[7];
    const float* bg2 = (const float*)d_in[8];
    const float* bb2 = (const float*)d_in[9];
    const float* bm2 = (const float*)d_in[10];
    const float* bv2 = (const float*)d_in[11];
    const float* cw3 = (const float*)d_in[12];
    const float* cb3 = (const float*)d_in[13];
    float* out = (float*)d_out;
    int* nbr = (int*)d_ws;                   // KNB * NQ ints = 1.18 MB

    hipLaunchKernelGGL(knn_idx, dim3(NB * (NP / QPB)), dim3(128), 0, stream, x, nbr);
    hipLaunchKernelGGL(umb_feat, dim3(NQ / 64), dim3(64), 0, stream,
                       x, nbr, cw1, bg1, bb1, bm1, bv1, cw2, cb2, bg2, bb2, bm2, bv2,
                       cw3, cb3, out);
}